// Round 17
// baseline (922.891 us; speedup 1.0000x reference)
//
#include <hip/hip_runtime.h>
#include <stdint.h>

#define B_DIM 512
#define I_DIM 128
#define H_DIM 128
#define NSTEP 511   // reference scans t = 0..T-2

typedef __attribute__((ext_vector_type(4))) float f32x4;
typedef _Float16 half2_t __attribute__((ext_vector_type(2)));
typedef _Float16 half8_t __attribute__((ext_vector_type(8)));

// Barrier draining ONLY LDS ops; global prefetches stay in flight across it.
#define BAR_LDS() asm volatile("s_waitcnt lgkmcnt(0)\n\ts_barrier" ::: "memory")
#define MFMA16(A, B, C) __builtin_amdgcn_mfma_f32_16x16x32_f16(A, B, C, 0, 0, 0)

__device__ __forceinline__ float frcp(float v) {
#if __has_builtin(__builtin_amdgcn_rcpf)
  return __builtin_amdgcn_rcpf(v);
#else
  return 1.f / v;
#endif
}
__device__ __forceinline__ unsigned pkrtz_u(float a, float b) {
#if __has_builtin(__builtin_amdgcn_cvt_pkrtz)
  return __builtin_bit_cast(unsigned, __builtin_amdgcn_cvt_pkrtz(a, b));
#else
  half2_t r; r.x = (_Float16)a; r.y = (_Float16)b;
  return __builtin_bit_cast(unsigned, r);
#endif
}

// ---------------------------------------------------------------------------
// Persistent split-pipeline GRU: 32 blocks x 16 rows, 1024 threads = 16 waves
// (4/SIMD). r17 = r15 (best, 532us) with x-role A-frags built DIRECTLY from
// global x (no xT staging): removes ~36KB/step from the contended LDS pipe
// (122->85 KB/step), moving it to the VMEM pipe (8KB tile, L1-resident).
// x(i+2) held in 32 VGPRs -> one full step of load slack. No setprio (r16
// regression); decode+NLL on h-wave 0 (r15 config).
// ---------------------------------------------------------------------------
__global__ __launch_bounds__(1024, 4) void k_rec(
    const float* __restrict__ x, const float* __restrict__ gt,
    const float* __restrict__ Wih, const float* __restrict__ Whh,
    const float* __restrict__ bih, const float* __restrict__ bhh,
    const float* __restrict__ Wdec, const float* __restrict__ bdec,
    float* __restrict__ nll_part) {
  __shared__ __align__(16) _Float16 hT[2][16 * 128];   // 8 KB h tiles
  __shared__ __align__(16) float pp[2][3][4][128][4];  // 48 KB x-preacts
  __shared__ float gl[NSTEP * 16];                     // 32.7 KB gt slice

  const int tid = threadIdx.x;
  const int lane = tid & 63;
  const int w = tid >> 6;                  // 0..15
  const int l15 = lane & 15, l4 = lane >> 4;
  const int row0 = blockIdx.x * 16;

  // ---- gt preload (all threads) ----
#pragma unroll
  for (int q = 0; q < 8; ++q) {
    const int idx = tid + 1024 * q;
    if (idx < NSTEP * 16)
      gl[idx] = gt[(size_t)((idx >> 4) + 1) * B_DIM + row0 + (idx & 15)];
  }

  if (w < 8) {
    // =========================== h-role ===========================
    const int u = 16 * w + l15;

    half8_t bh[3][4];
#pragma unroll
    for (int g3 = 0; g3 < 3; ++g3)
#pragma unroll
      for (int ks = 0; ks < 4; ++ks) {
        const size_t off = (size_t)(g3 * H_DIM + u) * H_DIM + ks * 32 + l4 * 8;
        const float4 a = *(const float4*)(Whh + off);
        const float4 b = *(const float4*)(Whh + off + 4);
        half8_t v;
        v[0] = (_Float16)a.x; v[1] = (_Float16)a.y;
        v[2] = (_Float16)a.z; v[3] = (_Float16)a.w;
        v[4] = (_Float16)b.x; v[5] = (_Float16)b.y;
        v[6] = (_Float16)b.z; v[7] = (_Float16)b.w;
        bh[g3][ks] = v;
      }
    half8_t wdB[4];
#pragma unroll
    for (int ks = 0; ks < 4; ++ks) {
      half8_t v;
#pragma unroll
      for (int j = 0; j < 8; ++j)
        v[j] = (l15 == 0) ? (_Float16)Wdec[ks * 32 + l4 * 8 + j] : (_Float16)0.f;
      wdB[ks] = v;
    }
    const float bhn = bhh[2 * H_DIM + u];
    const float bd0 = bdec[0];
    const f32x4 cN = (f32x4){bhn, bhn, bhn, bhn};

    // zero h(0) tile (h-threads cover the 4 KB)
    *(uint2*)((char*)hT[0] + tid * 8) = (uint2){0u, 0u};

    float h_old[4] = {0.f, 0.f, 0.f, 0.f};
    float nllA[4] = {0.f, 0.f, 0.f, 0.f};
    __syncthreads();   // A
    __syncthreads();   // B: pp[0] ready

#pragma unroll 1
    for (int i = 0; i < NSTEP; ++i) {
      const char* hb = (const char*)hT[i & 1];
      half8_t ah[4];
#pragma unroll
      for (int ks = 0; ks < 4; ++ks)
        ah[ks] = *(const half8_t*)(hb + l15 * 256 +
                                   ((((ks << 2) | l4) ^ l15) << 4));
      // x-side preacts as MFMA C-init (biases already folded by x-role)
      f32x4 aR = *(const f32x4*)&pp[i & 1][0][l4][u][0];
      f32x4 aZ = *(const f32x4*)&pp[i & 1][1][l4][u][0];
      const f32x4 pN = *(const f32x4*)&pp[i & 1][2][l4][u][0];
      f32x4 aN = cN;
#pragma unroll
      for (int ks = 0; ks < 4; ++ks) {
        aR = MFMA16(ah[ks], bh[0][ks], aR);
        aZ = MFMA16(ah[ks], bh[1][ks], aZ);
        aN = MFMA16(ah[ks], bh[2][ks], aN);
      }

      // decode + NLL for h(i) vs gt[i] (wave 0; epilogue covers h(511))
      if (w == 0 && i > 0) {
        f32x4 aD = (f32x4){0.f, 0.f, 0.f, 0.f};
#pragma unroll
        for (int ks = 0; ks < 4; ++ks) aD = MFMA16(ah[ks], wdB[ks], aD);
        if (l15 == 0) {
#pragma unroll
          for (int r = 0; r < 4; ++r) {
            const float C = frcp(1.f + __expf(-(aD[r] + bd0)));
            const float g = gl[(i - 1) * 16 + 4 * l4 + r];
            nllA[r] -= g * __logf(C + 1e-4f) +
                       (1.f - g) * __logf(1.f - C + 1e-4f);
          }
        }
      }

      // lean gate math; write hnew f16 into the other h tile
      char* hw = (char*)hT[(i + 1) & 1];
#pragma unroll
      for (int r = 0; r < 4; ++r) {
        const float r_ = frcp(1.f + __expf(-aR[r]));
        const float z_ = frcp(1.f + __expf(-aZ[r]));
        const float a2 = pN[r] + r_ * aN[r];
        const float n_ = 1.f - 2.f * frcp(__expf(2.f * a2) + 1.f);
        const float hnew = n_ + z_ * (h_old[r] - n_);
        h_old[r] = hnew;
        const int b = 4 * l4 + r;
        *(_Float16*)(hw + b * 256 + (((u >> 3) ^ b) << 4) + (u & 7) * 2) =
            (_Float16)hnew;
      }
      BAR_LDS();
    }

    // epilogue: decode h(511) vs gt[511]
    if (w == 0) {
      const char* hb = (const char*)hT[NSTEP & 1];
      half8_t ah[4];
#pragma unroll
      for (int ks = 0; ks < 4; ++ks)
        ah[ks] = *(const half8_t*)(hb + l15 * 256 +
                                   ((((ks << 2) | l4) ^ l15) << 4));
      f32x4 aD = (f32x4){0.f, 0.f, 0.f, 0.f};
#pragma unroll
      for (int ks = 0; ks < 4; ++ks) aD = MFMA16(ah[ks], wdB[ks], aD);
      if (l15 == 0) {
#pragma unroll
        for (int r = 0; r < 4; ++r) {
          const float C = frcp(1.f + __expf(-(aD[r] + bd0)));
          const float g = gl[(NSTEP - 1) * 16 + 4 * l4 + r];
          nllA[r] -= g * __logf(C + 1e-4f) +
                     (1.f - g) * __logf(1.f - C + 1e-4f);
          nll_part[row0 + 4 * l4 + r] = nllA[r];
        }
      }
    }
  } else {
    // =========================== x-role ===========================
    // A-frags straight from global x: lane (l15,l4) reads
    // x[t][row0+l15][ks*32 + l4*8 .. +8]  (two float4 per ks, L1-resident).
    const int u = 16 * (w - 8) + l15;

    half8_t bx[3][4];
#pragma unroll
    for (int g3 = 0; g3 < 3; ++g3)
#pragma unroll
      for (int ks = 0; ks < 4; ++ks) {
        const size_t off = (size_t)(g3 * H_DIM + u) * H_DIM + ks * 32 + l4 * 8;
        const float4 a = *(const float4*)(Wih + off);
        const float4 b = *(const float4*)(Wih + off + 4);
        half8_t v;
        v[0] = (_Float16)a.x; v[1] = (_Float16)a.y;
        v[2] = (_Float16)a.z; v[3] = (_Float16)a.w;
        v[4] = (_Float16)b.x; v[5] = (_Float16)b.y;
        v[6] = (_Float16)b.z; v[7] = (_Float16)b.w;
        bx[g3][ks] = v;
      }
    const float brz0 = bih[u] + bhh[u];
    const float brz1 = bih[H_DIM + u] + bhh[H_DIM + u];
    const float bxn = bih[2 * H_DIM + u];
    const f32x4 cR = (f32x4){brz0, brz0, brz0, brz0};
    const f32x4 cZ = (f32x4){brz1, brz1, brz1, brz1};
    const f32x4 cXN = (f32x4){bxn, bxn, bxn, bxn};

    // per-lane global base for A-frag reads
    const float* xl = x + (size_t)(row0 + l15) * I_DIM + l4 * 8;
    float4 xf[8];  // x(t) A-frag elements, fp32 (32 VGPR, 1 step of slack)
#pragma unroll
    for (int ks = 0; ks < 4; ++ks) {
      xf[2 * ks] = *(const float4*)(xl + ks * 32);
      xf[2 * ks + 1] = *(const float4*)(xl + ks * 32 + 4);
    }
    __syncthreads();   // A

    // pp[0] = x-part preacts for step 0
    {
      half8_t af[4];
#pragma unroll
      for (int ks = 0; ks < 4; ++ks) {
        uint2 p0, p1;
        p0.x = pkrtz_u(xf[2 * ks].x, xf[2 * ks].y);
        p0.y = pkrtz_u(xf[2 * ks].z, xf[2 * ks].w);
        p1.x = pkrtz_u(xf[2 * ks + 1].x, xf[2 * ks + 1].y);
        p1.y = pkrtz_u(xf[2 * ks + 1].z, xf[2 * ks + 1].w);
        uint4 q = {p0.x, p0.y, p1.x, p1.y};
        af[ks] = __builtin_bit_cast(half8_t, q);
      }
      f32x4 aR = cR, aZ = cZ, aN = cXN;
#pragma unroll
      for (int ks = 0; ks < 4; ++ks) {
        aR = MFMA16(af[ks], bx[0][ks], aR);
        aZ = MFMA16(af[ks], bx[1][ks], aZ);
        aN = MFMA16(af[ks], bx[2][ks], aN);
      }
      *(f32x4*)&pp[0][0][l4][u][0] = aR;
      *(f32x4*)&pp[0][1][l4][u][0] = aZ;
      *(f32x4*)&pp[0][2][l4][u][0] = aN;
    }
    // load x(1) into xf
#pragma unroll
    for (int ks = 0; ks < 4; ++ks) {
      const float* p = xl + (size_t)B_DIM * I_DIM + ks * 32;
      xf[2 * ks] = *(const float4*)p;
      xf[2 * ks + 1] = *(const float4*)(p + 4);
    }
    __syncthreads();   // B: pp[0] ready

#pragma unroll 1
    for (int i = 0; i < NSTEP; ++i) {
      // pp[(i+1)&1] from xf = x(i+1) (loaded one step ago)
      half8_t af[4];
#pragma unroll
      for (int ks = 0; ks < 4; ++ks) {
        uint2 p0, p1;
        p0.x = pkrtz_u(xf[2 * ks].x, xf[2 * ks].y);
        p0.y = pkrtz_u(xf[2 * ks].z, xf[2 * ks].w);
        p1.x = pkrtz_u(xf[2 * ks + 1].x, xf[2 * ks + 1].y);
        p1.y = pkrtz_u(xf[2 * ks + 1].z, xf[2 * ks + 1].w);
        uint4 q = {p0.x, p0.y, p1.x, p1.y};
        af[ks] = __builtin_bit_cast(half8_t, q);
      }
      f32x4 aR = cR, aZ = cZ, aN = cXN;
#pragma unroll
      for (int ks = 0; ks < 4; ++ks) {
        aR = MFMA16(af[ks], bx[0][ks], aR);
        aZ = MFMA16(af[ks], bx[1][ks], aZ);
        aN = MFMA16(af[ks], bx[2][ks], aN);
      }
      *(f32x4*)&pp[(i + 1) & 1][0][l4][u][0] = aR;
      *(f32x4*)&pp[(i + 1) & 1][1][l4][u][0] = aZ;
      *(f32x4*)&pp[(i + 1) & 1][2][l4][u][0] = aN;

      // issue loads for x(i+2) (clamped; consumed next iteration)
      {
        const size_t trow = (size_t)((i + 2 < 512) ? i + 2 : 511) * B_DIM * I_DIM;
#pragma unroll
        for (int ks = 0; ks < 4; ++ks) {
          const float* p = xl + trow + ks * 32;
          xf[2 * ks] = *(const float4*)p;
          xf[2 * ks + 1] = *(const float4*)(p + 4);
        }
      }
      BAR_LDS();
    }
  }
}

// ---------------------------------------------------------------------------
__global__ __launch_bounds__(512) void k_fin(const float* __restrict__ nll_part,
                                             float* __restrict__ out) {
  __shared__ float red[8];
  const int tid = threadIdx.x;
  float v = nll_part[tid];
#pragma unroll
  for (int off = 32; off; off >>= 1) v += __shfl_down(v, off);
  if ((tid & 63) == 0) red[tid >> 6] = v;
  __syncthreads();
  if (tid == 0) {
    float s = 0.f;
#pragma unroll
    for (int i = 0; i < 8; ++i) s += red[i];
    out[0] = s * (1.f / (512.f * 512.f));
  }
}

// ---------------------------------------------------------------------------
extern "C" void kernel_launch(void* const* d_in, const int* in_sizes, int n_in,
                              void* d_out, int out_size, void* d_ws,
                              size_t ws_size, hipStream_t stream) {
  const float* x    = (const float*)d_in[0];
  const float* gt   = (const float*)d_in[1];
  const float* Wih  = (const float*)d_in[2];
  const float* Whh  = (const float*)d_in[3];
  const float* bih  = (const float*)d_in[4];
  const float* bhh  = (const float*)d_in[5];
  const float* Wdec = (const float*)d_in[6];
  const float* bdec = (const float*)d_in[7];

  float* nll_part = (float*)d_ws;  // 512 floats, each written exactly once

  k_rec<<<dim3(32), dim3(1024), 0, stream>>>(
      x, gt, Wih, Whh, bih, bhh, Wdec, bdec, nll_part);
  k_fin<<<dim3(1), dim3(512), 0, stream>>>(nll_part, (float*)d_out);
}

// Round 18
// 519.345 us; speedup vs baseline: 1.7770x; 1.7770x over previous
//
#include <hip/hip_runtime.h>
#include <stdint.h>

#define B_DIM 512
#define I_DIM 128
#define H_DIM 128
#define NSTEP 511   // reference scans t = 0..T-2

typedef __attribute__((ext_vector_type(4))) float f32x4;
typedef _Float16 half2_t __attribute__((ext_vector_type(2)));
typedef _Float16 half8_t __attribute__((ext_vector_type(8)));

// Barrier draining ONLY LDS ops; global prefetches stay in flight across it.
#define BAR_LDS() asm volatile("s_waitcnt lgkmcnt(0)\n\ts_barrier" ::: "memory")
#define MFMA16(A, B, C) __builtin_amdgcn_mfma_f32_16x16x32_f16(A, B, C, 0, 0, 0)

__device__ __forceinline__ float frcp(float v) {
#if __has_builtin(__builtin_amdgcn_rcpf)
  return __builtin_amdgcn_rcpf(v);
#else
  return 1.f / v;
#endif
}
__device__ __forceinline__ unsigned pkrtz_u(float a, float b) {
#if __has_builtin(__builtin_amdgcn_cvt_pkrtz)
  return __builtin_bit_cast(unsigned, __builtin_amdgcn_cvt_pkrtz(a, b));
#else
  half2_t r; r.x = (_Float16)a; r.y = (_Float16)b;
  return __builtin_bit_cast(unsigned, r);
#endif
}
__device__ __forceinline__ uint2 pack_f32x4(f32x4 v) {
  uint2 p;
  p.x = pkrtz_u(v[0], v[1]);
  p.y = pkrtz_u(v[2], v[3]);
  return p;
}
__device__ __forceinline__ f32x4 unpack_u2(uint2 v) {
  const half2_t a = __builtin_bit_cast(half2_t, v.x);
  const half2_t b = __builtin_bit_cast(half2_t, v.y);
  return (f32x4){(float)a.x, (float)a.y, (float)b.x, (float)b.y};
}

// ---------------------------------------------------------------------------
// Persistent split-pipeline GRU: 32 blocks x 16 rows, 768 threads = 12 waves
// (3/SIMD: 2 h-waves + 1 x-wave each). r18 = r15 structure with LDS-pipe
// traffic cut 120->80 KB/step: (1) x-waves 8->4, each reads af ONCE and
// computes two 16-unit groups (af redundancy halved); (2) pp exchange in
// packed f16 (48->24 KB round-trip; h-side pays 12 cvt ~24cy to save ~190cy
// of DS pipe). No setprio (r16 reg.), LDS-staged x (r17 reg.).
// ---------------------------------------------------------------------------
__global__ __launch_bounds__(768, 3) void k_rec(
    const float* __restrict__ x, const float* __restrict__ gt,
    const float* __restrict__ Wih, const float* __restrict__ Whh,
    const float* __restrict__ bih, const float* __restrict__ bhh,
    const float* __restrict__ Wdec, const float* __restrict__ bdec,
    float* __restrict__ nll_part) {
  __shared__ __align__(16) _Float16 hT[2][16 * 128];   // 8 KB h tiles
  __shared__ __align__(16) _Float16 xT[2][16 * 128];   // 8 KB x tiles
  __shared__ __align__(16) uint2 pp[2][3][4][128];     // 24 KB f16 x-preacts
  __shared__ float gl[NSTEP * 16];                     // 32.7 KB gt slice

  const int tid = threadIdx.x;
  const int lane = tid & 63;
  const int w = tid >> 6;                  // 0..11
  const int l15 = lane & 15, l4 = lane >> 4;
  const int row0 = blockIdx.x * 16;

  // ---- gt preload (all threads) ----
#pragma unroll
  for (int q = 0; q < 11; ++q) {
    const int idx = tid + 768 * q;
    if (idx < NSTEP * 16)
      gl[idx] = gt[(size_t)((idx >> 4) + 1) * B_DIM + row0 + (idx & 15)];
  }

  if (w < 8) {
    // =========================== h-role ===========================
    const int u = 16 * w + l15;

    half8_t bh[3][4];
#pragma unroll
    for (int g3 = 0; g3 < 3; ++g3)
#pragma unroll
      for (int ks = 0; ks < 4; ++ks) {
        const size_t off = (size_t)(g3 * H_DIM + u) * H_DIM + ks * 32 + l4 * 8;
        const float4 a = *(const float4*)(Whh + off);
        const float4 b = *(const float4*)(Whh + off + 4);
        half8_t v;
        v[0] = (_Float16)a.x; v[1] = (_Float16)a.y;
        v[2] = (_Float16)a.z; v[3] = (_Float16)a.w;
        v[4] = (_Float16)b.x; v[5] = (_Float16)b.y;
        v[6] = (_Float16)b.z; v[7] = (_Float16)b.w;
        bh[g3][ks] = v;
      }
    half8_t wdB[4];
#pragma unroll
    for (int ks = 0; ks < 4; ++ks) {
      half8_t v;
#pragma unroll
      for (int j = 0; j < 8; ++j)
        v[j] = (l15 == 0) ? (_Float16)Wdec[ks * 32 + l4 * 8 + j] : (_Float16)0.f;
      wdB[ks] = v;
    }
    const float bhn = bhh[2 * H_DIM + u];
    const float bd0 = bdec[0];
    const f32x4 cN = (f32x4){bhn, bhn, bhn, bhn};

    // zero h(0) tile (512 h-threads cover the 4 KB)
    *(uint2*)((char*)hT[0] + tid * 8) = (uint2){0u, 0u};

    float h_old[4] = {0.f, 0.f, 0.f, 0.f};
    float nllA[4] = {0.f, 0.f, 0.f, 0.f};
    __syncthreads();   // A: hT[0] + xT staged
    __syncthreads();   // B: pp[0] ready

#pragma unroll 1
    for (int i = 0; i < NSTEP; ++i) {
      const char* hb = (const char*)hT[i & 1];
      half8_t ah[4];
#pragma unroll
      for (int ks = 0; ks < 4; ++ks)
        ah[ks] = *(const half8_t*)(hb + l15 * 256 +
                                   ((((ks << 2) | l4) ^ l15) << 4));
      // x-side preacts (f16-packed) as MFMA C-init
      f32x4 aR = unpack_u2(pp[i & 1][0][l4][u]);
      f32x4 aZ = unpack_u2(pp[i & 1][1][l4][u]);
      const f32x4 pN = unpack_u2(pp[i & 1][2][l4][u]);
      f32x4 aN = cN;
#pragma unroll
      for (int ks = 0; ks < 4; ++ks) {
        aR = MFMA16(ah[ks], bh[0][ks], aR);
        aZ = MFMA16(ah[ks], bh[1][ks], aZ);
        aN = MFMA16(ah[ks], bh[2][ks], aN);
      }

      // decode + NLL for h(i) vs gt[i] (wave 0; epilogue covers h(511))
      if (w == 0 && i > 0) {
        f32x4 aD = (f32x4){0.f, 0.f, 0.f, 0.f};
#pragma unroll
        for (int ks = 0; ks < 4; ++ks) aD = MFMA16(ah[ks], wdB[ks], aD);
        if (l15 == 0) {
#pragma unroll
          for (int r = 0; r < 4; ++r) {
            const float C = frcp(1.f + __expf(-(aD[r] + bd0)));
            const float g = gl[(i - 1) * 16 + 4 * l4 + r];
            nllA[r] -= g * __logf(C + 1e-4f) +
                       (1.f - g) * __logf(1.f - C + 1e-4f);
          }
        }
      }

      // lean gate math; write hnew f16 into the other h tile
      char* hw = (char*)hT[(i + 1) & 1];
#pragma unroll
      for (int r = 0; r < 4; ++r) {
        const float r_ = frcp(1.f + __expf(-aR[r]));
        const float z_ = frcp(1.f + __expf(-aZ[r]));
        const float a2 = pN[r] + r_ * aN[r];
        const float n_ = 1.f - 2.f * frcp(__expf(2.f * a2) + 1.f);
        const float hnew = n_ + z_ * (h_old[r] - n_);
        h_old[r] = hnew;
        const int b = 4 * l4 + r;
        *(_Float16*)(hw + b * 256 + (((u >> 3) ^ b) << 4) + (u & 7) * 2) =
            (_Float16)hnew;
      }
      BAR_LDS();
    }

    // epilogue: decode h(511) vs gt[511]
    if (w == 0) {
      const char* hb = (const char*)hT[NSTEP & 1];
      half8_t ah[4];
#pragma unroll
      for (int ks = 0; ks < 4; ++ks)
        ah[ks] = *(const half8_t*)(hb + l15 * 256 +
                                   ((((ks << 2) | l4) ^ l15) << 4));
      f32x4 aD = (f32x4){0.f, 0.f, 0.f, 0.f};
#pragma unroll
      for (int ks = 0; ks < 4; ++ks) aD = MFMA16(ah[ks], wdB[ks], aD);
      if (l15 == 0) {
#pragma unroll
        for (int r = 0; r < 4; ++r) {
          const float C = frcp(1.f + __expf(-(aD[r] + bd0)));
          const float g = gl[(NSTEP - 1) * 16 + 4 * l4 + r];
          nllA[r] -= g * __logf(C + 1e-4f) +
                     (1.f - g) * __logf(1.f - C + 1e-4f);
          nll_part[row0 + 4 * l4 + r] = nllA[r];
        }
      }
    }
  } else {
    // =========================== x-role ===========================
    // 4 waves; wave wx owns units 32wx..32wx+31 as two 16-unit groups
    // (u0 = 32wx+l15, u1 = u0+16). ONE af read feeds both groups.
    const int wx = w - 8;
    const int u0 = 32 * wx + l15;

    half8_t bx[2][3][4];
    float brz0[2], brz1[2], bxn[2];
#pragma unroll
    for (int c = 0; c < 2; ++c) {
      const int u = u0 + 16 * c;
#pragma unroll
      for (int g3 = 0; g3 < 3; ++g3)
#pragma unroll
        for (int ks = 0; ks < 4; ++ks) {
          const size_t off =
              (size_t)(g3 * H_DIM + u) * H_DIM + ks * 32 + l4 * 8;
          const float4 a = *(const float4*)(Wih + off);
          const float4 b = *(const float4*)(Wih + off + 4);
          half8_t v;
          v[0] = (_Float16)a.x; v[1] = (_Float16)a.y;
          v[2] = (_Float16)a.z; v[3] = (_Float16)a.w;
          v[4] = (_Float16)b.x; v[5] = (_Float16)b.y;
          v[6] = (_Float16)b.z; v[7] = (_Float16)b.w;
          bx[c][g3][ks] = v;
        }
      brz0[c] = bih[u] + bhh[u];
      brz1[c] = bih[H_DIM + u] + bhh[H_DIM + u];
      bxn[c] = bih[2 * H_DIM + u];
    }

    // staging identity: 256 x-threads, 16B (one uint4) each
    const int xt = tid - 512;            // 0..255
    const int sxr = xt >> 4;             // row 0..15
    const int c16 = xt & 15;             // 16B block 0..15
    const int sbyte = sxr * 256 + ((c16 ^ sxr) << 4);
    const size_t xlbase = ((size_t)row0 + sxr) * I_DIM + c16 * 8;

    // stage x(0), x(1); preload x(2)
    {
#pragma unroll
      for (int t = 0; t < 2; ++t) {
        const float4 v0 = *(const float4*)&x[(size_t)t * B_DIM * I_DIM + xlbase];
        const float4 v1 =
            *(const float4*)&x[(size_t)t * B_DIM * I_DIM + xlbase + 4];
        uint4 p;
        p.x = pkrtz_u(v0.x, v0.y);
        p.y = pkrtz_u(v0.z, v0.w);
        p.z = pkrtz_u(v1.x, v1.y);
        p.w = pkrtz_u(v1.z, v1.w);
        *(uint4*)((char*)xT[t] + sbyte) = p;
      }
    }
    float4 xA0 = *(const float4*)&x[(size_t)2 * B_DIM * I_DIM + xlbase];
    float4 xA1 = *(const float4*)&x[(size_t)2 * B_DIM * I_DIM + xlbase + 4];
    __syncthreads();   // A: xT[0], xT[1] staged

    // pp[0] = x-part preacts for step 0 (from xT[0])
    {
      const char* xb = (const char*)xT[0];
      half8_t af[4];
#pragma unroll
      for (int ks = 0; ks < 4; ++ks)
        af[ks] = *(const half8_t*)(xb + l15 * 256 +
                                   ((((ks << 2) | l4) ^ l15) << 4));
#pragma unroll
      for (int c = 0; c < 2; ++c) {
        f32x4 aR = (f32x4){brz0[c], brz0[c], brz0[c], brz0[c]};
        f32x4 aZ = (f32x4){brz1[c], brz1[c], brz1[c], brz1[c]};
        f32x4 aN = (f32x4){bxn[c], bxn[c], bxn[c], bxn[c]};
#pragma unroll
        for (int ks = 0; ks < 4; ++ks) {
          aR = MFMA16(af[ks], bx[c][0][ks], aR);
          aZ = MFMA16(af[ks], bx[c][1][ks], aZ);
          aN = MFMA16(af[ks], bx[c][2][ks], aN);
        }
        pp[0][0][l4][u0 + 16 * c] = pack_f32x4(aR);
        pp[0][1][l4][u0 + 16 * c] = pack_f32x4(aZ);
        pp[0][2][l4][u0 + 16 * c] = pack_f32x4(aN);
      }
    }
    __syncthreads();   // B: pp[0] ready

#pragma unroll 1
    for (int i = 0; i < NSTEP; ++i) {
      // x-part preacts for step i+1 (from xT[(i+1)&1], staged at iter i-1)
      const char* xb = (const char*)xT[(i + 1) & 1];
      half8_t af[4];
#pragma unroll
      for (int ks = 0; ks < 4; ++ks)
        af[ks] = *(const half8_t*)(xb + l15 * 256 +
                                   ((((ks << 2) | l4) ^ l15) << 4));
#pragma unroll
      for (int c = 0; c < 2; ++c) {
        f32x4 aR = (f32x4){brz0[c], brz0[c], brz0[c], brz0[c]};
        f32x4 aZ = (f32x4){brz1[c], brz1[c], brz1[c], brz1[c]};
        f32x4 aN = (f32x4){bxn[c], bxn[c], bxn[c], bxn[c]};
#pragma unroll
        for (int ks = 0; ks < 4; ++ks) {
          aR = MFMA16(af[ks], bx[c][0][ks], aR);
          aZ = MFMA16(af[ks], bx[c][1][ks], aZ);
          aN = MFMA16(af[ks], bx[c][2][ks], aN);
        }
        pp[(i + 1) & 1][0][l4][u0 + 16 * c] = pack_f32x4(aR);
        pp[(i + 1) & 1][1][l4][u0 + 16 * c] = pack_f32x4(aZ);
        pp[(i + 1) & 1][2][l4][u0 + 16 * c] = pack_f32x4(aN);
      }

      // stage x(i+2) from registers; issue loads for x(i+3)
      {
        uint4 p;
        p.x = pkrtz_u(xA0.x, xA0.y);
        p.y = pkrtz_u(xA0.z, xA0.w);
        p.z = pkrtz_u(xA1.x, xA1.y);
        p.w = pkrtz_u(xA1.z, xA1.w);
        *(uint4*)((char*)xT[i & 1] + sbyte) = p;
        const size_t trow =
            (size_t)((i + 3 < 512) ? i + 3 : 511) * B_DIM * I_DIM;
        xA0 = *(const float4*)&x[trow + xlbase];
        xA1 = *(const float4*)&x[trow + xlbase + 4];
      }
      BAR_LDS();
    }
  }
}

// ---------------------------------------------------------------------------
__global__ __launch_bounds__(512) void k_fin(const float* __restrict__ nll_part,
                                             float* __restrict__ out) {
  __shared__ float red[8];
  const int tid = threadIdx.x;
  float v = nll_part[tid];
#pragma unroll
  for (int off = 32; off; off >>= 1) v += __shfl_down(v, off);
  if ((tid & 63) == 0) red[tid >> 6] = v;
  __syncthreads();
  if (tid == 0) {
    float s = 0.f;
#pragma unroll
    for (int i = 0; i < 8; ++i) s += red[i];
    out[0] = s * (1.f / (512.f * 512.f));
  }
}

// ---------------------------------------------------------------------------
extern "C" void kernel_launch(void* const* d_in, const int* in_sizes, int n_in,
                              void* d_out, int out_size, void* d_ws,
                              size_t ws_size, hipStream_t stream) {
  const float* x    = (const float*)d_in[0];
  const float* gt   = (const float*)d_in[1];
  const float* Wih  = (const float*)d_in[2];
  const float* Whh  = (const float*)d_in[3];
  const float* bih  = (const float*)d_in[4];
  const float* bhh  = (const float*)d_in[5];
  const float* Wdec = (const float*)d_in[6];
  const float* bdec = (const float*)d_in[7];

  float* nll_part = (float*)d_ws;  // 512 floats, each written exactly once

  k_rec<<<dim3(32), dim3(768), 0, stream>>>(
      x, gt, Wih, Whh, bih, bhh, Wdec, bdec, nll_part);
  k_fin<<<dim3(1), dim3(512), 0, stream>>>(nll_part, (float*)d_out);
}